// Round 4
// baseline (451.227 us; speedup 1.0000x reference)
//
#include <hip/hip_runtime.h>

typedef unsigned short u16;
typedef unsigned int   u32;
typedef __bf16 bf16x8 __attribute__((ext_vector_type(8)));
typedef float  f32x4  __attribute__((ext_vector_type(4)));
typedef u32    u32x4  __attribute__((ext_vector_type(4)));
typedef u16    u16x8  __attribute__((ext_vector_type(8)));

#define MFMA16(a,b,c) __builtin_amdgcn_mfma_f32_16x16x32_bf16(a,b,c,0,0,0)

#define BB 4
#define SS 2048
#define DD 1024
#define HH 16
#define DH 64
#define MM 8192   // B*S

#define GSTR 56   // GEMM LDS row stride (u16): 112B rows -> 16B aligned, 2-way banks
#define KSTR 72   // attn LDS row stride (u16): 144B rows -> 16B aligned, 2-way banks

#define NEG_BIG (-1e30f)

__device__ __forceinline__ u16 f2bf(float f) {
  u32 u = __builtin_bit_cast(u32, f);
  u += 0x7fffu + ((u >> 16) & 1u);   // RNE
  return (u16)(u >> 16);
}

// ---------------------------------------------------------------------------
// Kernel 0: x fp32 [8192*1024] -> bf16
// ---------------------------------------------------------------------------
__global__ __launch_bounds__(256) void convert_x(
    const float* __restrict__ in, u16* __restrict__ out)
{
  const size_t stride = (size_t)gridDim.x * 256 * 8;
  for (size_t i = ((size_t)blockIdx.x * 256 + threadIdx.x) * 8;
       i < (size_t)MM * DD; i += stride) {
    f32x4 a = *(const f32x4*)(in + i);
    f32x4 b = *(const f32x4*)(in + i + 4);
    u16x8 v;
#pragma unroll
    for (int j = 0; j < 4; ++j) { v[j] = f2bf(a[j]); v[j + 4] = f2bf(b[j]); }
    *(u16x8*)(out + i) = v;
  }
}

// ---------------------------------------------------------------------------
// Kernel 0b: ws-too-small signature
// ---------------------------------------------------------------------------
__global__ __launch_bounds__(256) void fill_sig(float* __restrict__ out, int n)
{
  for (int i = blockIdx.x * 256 + threadIdx.x; i < n; i += gridDim.x * 256)
    out[i] = 3.0f;
}

// ---------------------------------------------------------------------------
// Kernel 1: W fp32 [K][N] -> Wt bf16 [N][K] for the three projection weights
// ---------------------------------------------------------------------------
__global__ __launch_bounds__(256) void convert_w(
    const float* __restrict__ w0, const float* __restrict__ w1,
    const float* __restrict__ w2, u16* __restrict__ WtAll)
{
  const int z = blockIdx.z;
  const float* W = (z == 0) ? w0 : ((z == 1) ? w1 : w2);
  u16* Wt = WtAll + (size_t)z * DD * DD;
  const int n0 = blockIdx.x * 64;
  const int k0 = blockIdx.y * 64;
  __shared__ u16 tile[64][65];
#pragma unroll
  for (int i = 0; i < 16; ++i) {
    int e = threadIdx.x + i * 256;
    int r = e >> 6, c = e & 63;
    tile[r][c] = f2bf(W[(size_t)(k0 + r) * DD + n0 + c]);
  }
  __syncthreads();
#pragma unroll
  for (int i = 0; i < 16; ++i) {
    int e = threadIdx.x + i * 256;
    int r = e >> 6, c = e & 63;
    Wt[(size_t)(n0 + r) * DD + k0 + c] = tile[c][r];
  }
}

// ---------------------------------------------------------------------------
// Kernel 2: Y[z] = Xs (8192x1024) * W[z] (1024x1024) bf16, z in {Q,K,V}
// 128x128 tile / block, 4 waves as 2x2, each wave 64x64 via 4x4 mfma 16x16x32
// ---------------------------------------------------------------------------
__global__ __launch_bounds__(256) void qkv_gemm(
    const u16* __restrict__ X, const u16* __restrict__ WtAll,
    u16* __restrict__ QKV)
{
  const int z = blockIdx.z;
  const u16* Wt = WtAll + (size_t)z * DD * DD;
  u16* Y = QKV + (size_t)z * MM * DD;
  const int m0 = blockIdx.x * 128;
  const int n0 = blockIdx.y * 128;
  const int t = threadIdx.x;
  const int lane = t & 63;
  const int wave = t >> 6;
  const int cl = lane & 15;
  const int qd = lane >> 4;
  const int wm = (wave & 1) * 64;
  const int wn = (wave >> 1) * 64;

  __shared__ u16 Al[128 * GSTR];
  __shared__ u16 Bl[128 * GSTR];

  const f32x4 fzero = {0.f, 0.f, 0.f, 0.f};
  f32x4 acc[4][4];
#pragma unroll
  for (int i = 0; i < 4; ++i)
#pragma unroll
    for (int j = 0; j < 4; ++j) acc[i][j] = fzero;

  const int sr  = t >> 2;
  const int sc8 = (t & 3) * 8;
  const u16* gA0 = X  + (size_t)(m0 + sr) * DD + sc8;
  const u16* gA1 = X  + (size_t)(m0 + 64 + sr) * DD + sc8;
  const u16* gB0 = Wt + (size_t)(n0 + sr) * DD + sc8;
  const u16* gB1 = Wt + (size_t)(n0 + 64 + sr) * DD + sc8;

  for (int k0 = 0; k0 < DD; k0 += 32) {
    u32x4 a0 = *(const u32x4*)(gA0 + k0);
    u32x4 a1 = *(const u32x4*)(gA1 + k0);
    u32x4 b0 = *(const u32x4*)(gB0 + k0);
    u32x4 b1 = *(const u32x4*)(gB1 + k0);
    __syncthreads();
    *(u32x4*)&Al[sr * GSTR + sc8]        = a0;
    *(u32x4*)&Al[(64 + sr) * GSTR + sc8] = a1;
    *(u32x4*)&Bl[sr * GSTR + sc8]        = b0;
    *(u32x4*)&Bl[(64 + sr) * GSTR + sc8] = b1;
    __syncthreads();

    bf16x8 af[4], bf[4];
#pragma unroll
    for (int mb = 0; mb < 4; ++mb)
      af[mb] = *(const bf16x8*)&Al[(wm + mb * 16 + cl) * GSTR + qd * 8];
#pragma unroll
    for (int nb = 0; nb < 4; ++nb)
      bf[nb] = *(const bf16x8*)&Bl[(wn + nb * 16 + cl) * GSTR + qd * 8];
#pragma unroll
    for (int mb = 0; mb < 4; ++mb)
#pragma unroll
      for (int nb = 0; nb < 4; ++nb)
        acc[mb][nb] = MFMA16(af[mb], bf[nb], acc[mb][nb]);
  }

#pragma unroll
  for (int mb = 0; mb < 4; ++mb) {
#pragma unroll
    for (int r = 0; r < 4; ++r) {
      const size_t row = (size_t)(m0 + wm + mb * 16 + qd * 4 + r) * DD;
#pragma unroll
      for (int nb = 0; nb < 4; ++nb)
        Y[row + n0 + wn + nb * 16 + cl] = f2bf(acc[mb][nb][r]);
    }
  }
}

// ---------------------------------------------------------------------------
// Kernel 3: flash attention. Block = 64 q-rows x one (b,h); 4 waves of 16
// q-rows. K-tiles of 64 keys. Online softmax, log2 domain, fp32 out.
// ---------------------------------------------------------------------------
__global__ __launch_bounds__(256) void attn_kernel(
    const u16* __restrict__ QKV, float* __restrict__ Out)
{
  const int b = blockIdx.z;
  const int h = blockIdx.y;
  const int q0 = blockIdx.x * 64;
  const int t = threadIdx.x;
  const int lane = t & 63;
  const int wave = t >> 6;
  const int cl = lane & 15;
  const int qd = lane >> 4;

  const u16* Q = QKV;
  const u16* K = QKV + (size_t)MM * DD;
  const u16* V = QKV + (size_t)2 * MM * DD;

  __shared__ u16 Kl[64 * KSTR];
  __shared__ u16 Vt[64 * KSTR];           // V transposed: Vt[d][key]
  __shared__ u16 Pl[4 * 16 * KSTR];       // per-wave P tile, row-major

  bf16x8 qf0, qf1;
  {
    const size_t qoff = (size_t)(b * SS + q0 + wave * 16 + cl) * DD + h * DH;
    qf0 = *(const bf16x8*)(Q + qoff + qd * 8);
    qf1 = *(const bf16x8*)(Q + qoff + 32 + qd * 8);
  }

  const f32x4 fzero = {0.f, 0.f, 0.f, 0.f};
  float mrow[4], lrow[4];
  f32x4 oacc[4];
#pragma unroll
  for (int r = 0; r < 4; ++r) { mrow[r] = NEG_BIG; lrow[r] = 0.f; }
#pragma unroll
  for (int d = 0; d < 4; ++d) oacc[d] = fzero;

  const float sc = 0.0625f * 1.4426950408889634f;  // (1/H) * log2(e)

  const int kr = t >> 3;
  const int kc = (t & 7) * 8;
  const int sw = (t & 7) ^ (kr & 7);

  for (int kt = 0; kt < SS; kt += 64) {
    const size_t kbase = (size_t)(b * SS + kt) * DD + h * DH;
    u32x4 kv0 = *(const u32x4*)(K + kbase + (size_t)kr * DD + kc);
    u32x4 kv1 = *(const u32x4*)(K + kbase + (size_t)(kr + 32) * DD + kc);
    u32x4 vv0 = *(const u32x4*)(V + kbase + (size_t)kr * DD + kc);
    u32x4 vv1 = *(const u32x4*)(V + kbase + (size_t)(kr + 32) * DD + kc);

    __syncthreads();

    *(u32x4*)&Kl[kr * KSTR + kc]        = kv0;
    *(u32x4*)&Kl[(kr + 32) * KSTR + kc] = kv1;

    u16x8 v0s = __builtin_bit_cast(u16x8, vv0);
    u16x8 v1s = __builtin_bit_cast(u16x8, vv1);
#pragma unroll
    for (int j = 0; j < 8; ++j) {
      int ej = j ^ sw;
      Vt[(kc + ej) * KSTR + kr]      = v0s[ej];
      Vt[(kc + ej) * KSTR + kr + 32] = v1s[ej];
    }

    __syncthreads();

    f32x4 s[4];
#pragma unroll
    for (int nb = 0; nb < 4; ++nb) {
      bf16x8 kf0 = *(const bf16x8*)&Kl[(nb * 16 + cl) * KSTR + qd * 8];
      bf16x8 kf1 = *(const bf16x8*)&Kl[(nb * 16 + cl) * KSTR + 32 + qd * 8];
      f32x4 zacc = fzero;
      zacc = MFMA16(qf0, kf0, zacc);
      zacc = MFMA16(qf1, kf1, zacc);
      s[nb] = zacc;
    }

    float mt[4], al[4], p[4][4];
#pragma unroll
    for (int r = 0; r < 4; ++r) {
      float v = fmaxf(fmaxf(s[0][r], s[1][r]), fmaxf(s[2][r], s[3][r])) * sc;
#pragma unroll
      for (int d = 1; d < 16; d <<= 1) v = fmaxf(v, __shfl_xor(v, d));
      mt[r] = v;
    }
#pragma unroll
    for (int r = 0; r < 4; ++r) {
      float mn = fmaxf(mrow[r], mt[r]);
      al[r] = exp2f(fminf(mrow[r] - mn, 0.f));
      mrow[r] = mn;
    }
#pragma unroll
    for (int nb = 0; nb < 4; ++nb)
#pragma unroll
      for (int r = 0; r < 4; ++r)
        p[nb][r] = exp2f(fminf(s[nb][r] * sc - mrow[r], 0.f));
#pragma unroll
    for (int r = 0; r < 4; ++r) {
      float v = p[0][r] + p[1][r] + p[2][r] + p[3][r];
#pragma unroll
      for (int d = 1; d < 16; d <<= 1) v += __shfl_xor(v, d);
      lrow[r] = lrow[r] * al[r] + v;
    }
#pragma unroll
    for (int db = 0; db < 4; ++db)
#pragma unroll
      for (int r = 0; r < 4; ++r)
        oacc[db][r] *= al[r];

    u16* Pw = &Pl[wave * 16 * KSTR];
#pragma unroll
    for (int nb = 0; nb < 4; ++nb)
#pragma unroll
      for (int r = 0; r < 4; ++r)
        Pw[(qd * 4 + r) * KSTR + nb * 16 + cl] = f2bf(p[nb][r]);

    __syncthreads();

    bf16x8 pf0 = *(const bf16x8*)&Pl[(wave * 16 + cl) * KSTR + qd * 8];
    bf16x8 pf1 = *(const bf16x8*)&Pl[(wave * 16 + cl) * KSTR + 32 + qd * 8];
#pragma unroll
    for (int db = 0; db < 4; ++db) {
      bf16x8 vf0 = *(const bf16x8*)&Vt[(db * 16 + cl) * KSTR + qd * 8];
      bf16x8 vf1 = *(const bf16x8*)&Vt[(db * 16 + cl) * KSTR + 32 + qd * 8];
      oacc[db] = MFMA16(pf0, vf0, oacc[db]);
      oacc[db] = MFMA16(pf1, vf1, oacc[db]);
    }
  }

#pragma unroll
  for (int r = 0; r < 4; ++r) {
    const float inv = 1.f / fmaxf(lrow[r], 1e-30f);
    const size_t row =
        (size_t)(b * SS + q0 + wave * 16 + qd * 4 + r) * DD + h * DH;
#pragma unroll
    for (int db = 0; db < 4; ++db)
      Out[row + db * 16 + cl] = oacc[db][r] * inv;   // fp32 store
  }
}

// ---------------------------------------------------------------------------
extern "C" void kernel_launch(void* const* d_in, const int* in_sizes, int n_in,
                              void* d_out, int out_size, void* d_ws, size_t ws_size,
                              hipStream_t stream)
{
  // fp32 I/O per the reference (float32 everywhere); bf16 compute internally.
  const float* x  = (const float*)d_in[0];
  const float* wq = (const float*)d_in[1];
  const float* wk = (const float*)d_in[2];
  const float* wv = (const float*)d_in[3];
  float* out = (float*)d_out;

  // ws layout (bf16): xs (16 MB) | wt (6 MB) | qkv (48 MB)
  const size_t need =
      ((size_t)MM * DD + 3 * (size_t)DD * DD + 3 * (size_t)MM * DD) * sizeof(u16);
  if (ws_size < need) {
    fill_sig<<<1024, 256, 0, stream>>>(out, out_size);
    return;
  }

  u16* xs  = (u16*)d_ws;
  u16* wt  = xs + (size_t)MM * DD;
  u16* qkv = wt + (size_t)3 * DD * DD;

  convert_x<<<2048, 256, 0, stream>>>(x, xs);
  convert_w<<<dim3(16, 16, 3), 256, 0, stream>>>(wq, wk, wv, wt);
  qkv_gemm  <<<dim3(64, 8, 3),  256, 0, stream>>>(xs, wt, qkv);
  attn_kernel<<<dim3(32, HH, BB), 256, 0, stream>>>(qkv, out);
}

// Round 5
// 332.893 us; speedup vs baseline: 1.3555x; 1.3555x over previous
//
#include <hip/hip_runtime.h>

typedef unsigned short u16;
typedef unsigned int   u32;
typedef __bf16 bf16x8 __attribute__((ext_vector_type(8)));
typedef float  f32x4  __attribute__((ext_vector_type(4)));
typedef u32    u32x4  __attribute__((ext_vector_type(4)));
typedef u32    u32x2  __attribute__((ext_vector_type(2)));
typedef u16    u16x8  __attribute__((ext_vector_type(8)));

#define MFMA16(a,b,c) __builtin_amdgcn_mfma_f32_16x16x32_bf16(a,b,c,0,0,0)

#define BB 4
#define SS 2048
#define DD 1024
#define HH 16
#define DH 64
#define MM 8192   // B*S

#define NEG_BIG (-1e30f)

__device__ __forceinline__ u16 f2bf(float f) {
  u32 u = __builtin_bit_cast(u32, f);
  u += 0x7fffu + ((u >> 16) & 1u);   // RNE
  return (u16)(u >> 16);
}

// async global->LDS DMA, 16B per lane. LDS dest = wave-uniform base + lane*16.
__device__ __forceinline__ void async16(const void* g, void* l) {
  __builtin_amdgcn_global_load_lds(
      (const __attribute__((address_space(1))) unsigned int*)g,
      (__attribute__((address_space(3))) unsigned int*)l, 16, 0, 0);
}

// ---------------------------------------------------------------------------
// Kernel 0: x fp32 -> bf16
// ---------------------------------------------------------------------------
__global__ __launch_bounds__(256) void convert_x(
    const float* __restrict__ in, u16* __restrict__ out)
{
  const size_t stride = (size_t)gridDim.x * 256 * 8;
  for (size_t i = ((size_t)blockIdx.x * 256 + threadIdx.x) * 8;
       i < (size_t)MM * DD; i += stride) {
    f32x4 a = *(const f32x4*)(in + i);
    f32x4 b = *(const f32x4*)(in + i + 4);
    u16x8 v;
#pragma unroll
    for (int j = 0; j < 4; ++j) { v[j] = f2bf(a[j]); v[j + 4] = f2bf(b[j]); }
    *(u16x8*)(out + i) = v;
  }
}

__global__ __launch_bounds__(256) void fill_sig(float* __restrict__ out, int n)
{
  for (int i = blockIdx.x * 256 + threadIdx.x; i < n; i += gridDim.x * 256)
    out[i] = 3.0f;
}

// ---------------------------------------------------------------------------
// Kernel 1: W fp32 [K][N] -> Wt bf16 [N][K]
// ---------------------------------------------------------------------------
__global__ __launch_bounds__(256) void convert_w(
    const float* __restrict__ w0, const float* __restrict__ w1,
    const float* __restrict__ w2, u16* __restrict__ WtAll)
{
  const int z = blockIdx.z;
  const float* W = (z == 0) ? w0 : ((z == 1) ? w1 : w2);
  u16* Wt = WtAll + (size_t)z * DD * DD;
  const int n0 = blockIdx.x * 64;
  const int k0 = blockIdx.y * 64;
  __shared__ u16 tile[64][65];
#pragma unroll
  for (int i = 0; i < 16; ++i) {
    int e = threadIdx.x + i * 256;
    int r = e >> 6, c = e & 63;
    tile[r][c] = f2bf(W[(size_t)(k0 + r) * DD + n0 + c]);
  }
  __syncthreads();
#pragma unroll
  for (int i = 0; i < 16; ++i) {
    int e = threadIdx.x + i * 256;
    int r = e >> 6, c = e & 63;
    Wt[(size_t)(n0 + r) * DD + k0 + c] = tile[c][r];
  }
}

// ---------------------------------------------------------------------------
// Kernel 2: QKV GEMM, 128x128 tile, async global_load_lds staging (m97 style)
// LDS tiles unpadded [128][32]: lane i of a wave lands at base + i*16B.
// ---------------------------------------------------------------------------
__global__ __launch_bounds__(256) void qkv_gemm(
    const u16* __restrict__ X, const u16* __restrict__ WtAll,
    u16* __restrict__ QKV)
{
  const int z = blockIdx.z;
  const u16* Wt = WtAll + (size_t)z * DD * DD;
  u16* Y = QKV + (size_t)z * MM * DD;
  const int m0 = blockIdx.x * 128;
  const int n0 = blockIdx.y * 128;
  const int t = threadIdx.x;
  const int ln = t & 63;
  const int w  = t >> 6;
  const int cl = ln & 15;
  const int qd = ln >> 4;
  const int wm = (w & 1) * 64;
  const int wn = (w >> 1) * 64;
  const int srow   = ln >> 2;        // 0..15 rows per wave sweep
  const int schunk = (ln & 3) * 8;   // u16 col offset

  __shared__ __align__(16) u16 Asm[128 * 32];
  __shared__ __align__(16) u16 Bsm[128 * 32];

  const f32x4 fzero = {0.f, 0.f, 0.f, 0.f};
  f32x4 acc[4][4];
#pragma unroll
  for (int i = 0; i < 4; ++i)
#pragma unroll
    for (int j = 0; j < 4; ++j) acc[i][j] = fzero;

  for (int k0 = 0; k0 < DD; k0 += 32) {
    __syncthreads();   // prior iteration's LDS reads done
#pragma unroll
    for (int c = 0; c < 2; ++c) {
      async16(X  + (size_t)(m0 + c * 64 + w * 16 + srow) * DD + k0 + schunk,
              Asm + (c * 64 + w * 16) * 32);
      async16(Wt + (size_t)(n0 + c * 64 + w * 16 + srow) * DD + k0 + schunk,
              Bsm + (c * 64 + w * 16) * 32);
    }
    __syncthreads();   // vmcnt drained by barrier semantics

    bf16x8 af[4], bf[4];
#pragma unroll
    for (int mb = 0; mb < 4; ++mb)
      af[mb] = *(const bf16x8*)&Asm[(wm + mb * 16 + cl) * 32 + qd * 8];
#pragma unroll
    for (int nb = 0; nb < 4; ++nb)
      bf[nb] = *(const bf16x8*)&Bsm[(wn + nb * 16 + cl) * 32 + qd * 8];
#pragma unroll
    for (int mb = 0; mb < 4; ++mb)
#pragma unroll
      for (int nb = 0; nb < 4; ++nb)
        acc[mb][nb] = MFMA16(af[mb], bf[nb], acc[mb][nb]);
  }

#pragma unroll
  for (int mb = 0; mb < 4; ++mb) {
#pragma unroll
    for (int r = 0; r < 4; ++r) {
      const size_t row = (size_t)(m0 + wm + mb * 16 + qd * 4 + r) * DD;
#pragma unroll
      for (int nb = 0; nb < 4; ++nb)
        Y[row + n0 + wn + nb * 16 + cl] = f2bf(acc[mb][nb][r]);
    }
  }
}

// ---------------------------------------------------------------------------
// Kernel 2b: V [MM][DD] -> VtG [b][h][d=64][s=2048]  (one-time transpose)
// ---------------------------------------------------------------------------
__global__ __launch_bounds__(256) void vtrans(
    const u16* __restrict__ V, u16* __restrict__ VtG)
{
  const int b = blockIdx.z;
  const int h = blockIdx.y;
  const int s0 = blockIdx.x * 64;
  __shared__ u16 tile[64][65];
#pragma unroll
  for (int i = 0; i < 16; ++i) {
    int e = threadIdx.x + i * 256;
    int r = e >> 6, c = e & 63;   // r = s offset, c = d
    tile[r][c] = V[(size_t)(b * SS + s0 + r) * DD + h * DH + c];
  }
  __syncthreads();
#pragma unroll
  for (int i = 0; i < 16; ++i) {
    int e = threadIdx.x + i * 256;
    int r = e >> 6, c = e & 63;   // r = d, c = s offset
    VtG[((size_t)(b * HH + h) * DH + r) * SS + s0 + c] = tile[c][r];
  }
}

// ---------------------------------------------------------------------------
// Kernel 3: flash attention, transposed formulation.
//   S^T = K·Q^T  (per wave: 64 keys x 16 q)  -> lane holds 16 scores, all q=cl
//   softmax: in-lane reduce + 2 shuffles (xor 16,32) for max and sum
//   O^T = V^T·P^T; O^T transposed back via per-wave LDS pass in epilogue.
// Staging via global_load_lds into unpadded [2][64][32] half-tiles.
// ---------------------------------------------------------------------------
__global__ __launch_bounds__(256) void attn_kernel(
    const u16* __restrict__ QKV, const u16* __restrict__ VtG,
    float* __restrict__ Out)
{
  const int b = blockIdx.z;
  const int h = blockIdx.y;
  const int q0 = blockIdx.x * 64;
  const int t = threadIdx.x;
  const int ln = t & 63;
  const int w  = t >> 6;
  const int cl = ln & 15;
  const int qd = ln >> 4;
  const int srow   = ln >> 2;
  const int schunk = (ln & 3) * 8;

  const u16* Qg = QKV;
  const u16* Kg = QKV + (size_t)MM * DD;

  // smem: Kh [2][64][32] | Vh [2][64][32] | Pl [4][16][72]; epilogue overlays
  // Ol [4][16][68] fp32 (17408 B < 25600 B).
  __shared__ __align__(16) u16 smem[12800];
  u16* Kh = smem;
  u16* Vh = smem + 4096;
  u16* Pl = smem + 8192;

  // Q fragments (resident): frag[m=cl][k=qd*8+j] = Q[q0+w*16+cl][qd*8+j (+32)]
  const size_t qoff = (size_t)(b * SS + q0 + w * 16 + cl) * DD + h * DH;
  const bf16x8 qf0 = *(const bf16x8*)(Qg + qoff + qd * 8);
  const bf16x8 qf1 = *(const bf16x8*)(Qg + qoff + 32 + qd * 8);

  const f32x4 fzero = {0.f, 0.f, 0.f, 0.f};
  f32x4 oacc[4];
#pragma unroll
  for (int mt = 0; mt < 4; ++mt) oacc[mt] = fzero;
  float mrow = NEG_BIG, lrow = 0.f;

  const float sc = 0.0625f * 1.4426950408889634f;  // (1/H)*log2(e)

  const size_t kgbase  = (size_t)b * SS * DD + (size_t)h * DH;
  const size_t vtgbase = ((size_t)(b * HH + h)) * DH * SS;

  for (int kt = 0; kt < SS; kt += 64) {
    __syncthreads();   // previous tile's LDS reads complete
#pragma unroll
    for (int s = 0; s < 2; ++s) {
      async16(Kg  + kgbase + (size_t)(kt + w * 16 + srow) * DD + s * 32 + schunk,
              Kh + (s * 64 + w * 16) * 32);
      async16(VtG + vtgbase + (size_t)(w * 16 + srow) * SS + kt + s * 32 + schunk,
              Vh + (s * 64 + w * 16) * 32);
    }
    __syncthreads();   // staged (barrier drains vmcnt)

    // S^T tiles: st[mt] holds S^T[key = mt*16 + qd*4 + r][q = cl]
    f32x4 st[4];
#pragma unroll
    for (int mt = 0; mt < 4; ++mt) {
      bf16x8 kf0 = *(const bf16x8*)&Kh[(mt * 16 + cl) * 32 + qd * 8];
      bf16x8 kf1 = *(const bf16x8*)&Kh[(64 + mt * 16 + cl) * 32 + qd * 8];
      f32x4 z = fzero;
      z = MFMA16(kf0, qf0, z);
      z = MFMA16(kf1, qf1, z);
      st[mt] = z;
    }

    // online softmax for q = cl: 16 in-lane values + cross-qd (xor 16,32)
    float mx = st[0][0];
#pragma unroll
    for (int mt = 0; mt < 4; ++mt)
#pragma unroll
      for (int r = 0; r < 4; ++r) mx = fmaxf(mx, st[mt][r]);
    mx = fmaxf(mx, __shfl_xor(mx, 16));
    mx = fmaxf(mx, __shfl_xor(mx, 32));
    mx *= sc;
    const float mn  = fmaxf(mrow, mx);
    const float alv = exp2f(fminf(mrow - mn, 0.f));
    mrow = mn;

    float p[4][4];
    float sum = 0.f;
#pragma unroll
    for (int mt = 0; mt < 4; ++mt)
#pragma unroll
      for (int r = 0; r < 4; ++r) {
        p[mt][r] = exp2f(fminf(st[mt][r] * sc - mn, 0.f));
        sum += p[mt][r];
      }
    sum += __shfl_xor(sum, 16);
    sum += __shfl_xor(sum, 32);
    lrow = lrow * alv + sum;
#pragma unroll
    for (int mt = 0; mt < 4; ++mt)
#pragma unroll
      for (int r = 0; r < 4; ++r) oacc[mt][r] *= alv;

    // P to LDS row-major [q=cl][k]: lane's 4 values per mt are k-contiguous
    u16* Pw = Pl + (w * 16 + cl) * 72;
#pragma unroll
    for (int mt = 0; mt < 4; ++mt) {
      u32 lo = (u32)f2bf(p[mt][0]) | ((u32)f2bf(p[mt][1]) << 16);
      u32 hi = (u32)f2bf(p[mt][2]) | ((u32)f2bf(p[mt][3]) << 16);
      u32x2 v = {lo, hi};
      *(u32x2*)(Pw + mt * 16 + qd * 4) = v;   // 8B write
    }
    // same-wave LDS ops complete in order: no barrier needed (per-wave P tile)
    const bf16x8 pf0 = *(const bf16x8*)&Pl[(w * 16 + cl) * 72 + qd * 8];
    const bf16x8 pf1 = *(const bf16x8*)&Pl[(w * 16 + cl) * 72 + 32 + qd * 8];

    // O^T += V^T · P^T : oacc[mt] holds O^T[d = mt*16 + qd*4 + r][q = cl]
#pragma unroll
    for (int mt = 0; mt < 4; ++mt) {
      bf16x8 vf0 = *(const bf16x8*)&Vh[(mt * 16 + cl) * 32 + qd * 8];
      bf16x8 vf1 = *(const bf16x8*)&Vh[(64 + mt * 16 + cl) * 32 + qd * 8];
      oacc[mt] = MFMA16(vf0, pf0, oacc[mt]);
      oacc[mt] = MFMA16(vf1, pf1, oacc[mt]);
    }
  }

  // epilogue: normalize, transpose O^T -> O via per-wave LDS pass, store fp32
  __syncthreads();                 // staging arrays dead; overlay Ol
  float* Ol = (float*)smem;        // [4][16][68]
  const float inv = 1.f / fmaxf(lrow, 1e-30f);
#pragma unroll
  for (int mt = 0; mt < 4; ++mt) {
    f32x4 vv = oacc[mt];
#pragma unroll
    for (int r = 0; r < 4; ++r) vv[r] *= inv;
    *(f32x4*)(Ol + w * 1088 + cl * 68 + mt * 16 + qd * 4) = vv;
  }
  // same-wave read-back (in-order LDS), coalesced global store
  const int q   = ln >> 2;
  const int seg = ln & 3;
  const float* src = Ol + w * 1088 + q * 68 + seg * 16;
  float* dst = Out + (size_t)(b * SS + q0 + w * 16 + q) * DD + h * DH + seg * 16;
#pragma unroll
  for (int i = 0; i < 4; ++i)
    *(f32x4*)(dst + i * 4) = *(const f32x4*)(src + i * 4);
}

// ---------------------------------------------------------------------------
extern "C" void kernel_launch(void* const* d_in, const int* in_sizes, int n_in,
                              void* d_out, int out_size, void* d_ws, size_t ws_size,
                              hipStream_t stream)
{
  const float* x  = (const float*)d_in[0];
  const float* wq = (const float*)d_in[1];
  const float* wk = (const float*)d_in[2];
  const float* wv = (const float*)d_in[3];
  float* out = (float*)d_out;

  // ws (bf16): xs 16MB | wt 6MB | qkv 48MB | vtg 16MB  = 86MB
  const size_t need = ((size_t)MM * DD + 3 * (size_t)DD * DD +
                       3 * (size_t)MM * DD + (size_t)MM * DD) * sizeof(u16);
  if (ws_size < need) {
    fill_sig<<<1024, 256, 0, stream>>>(out, out_size);
    return;
  }

  u16* xs  = (u16*)d_ws;
  u16* wt  = xs + (size_t)MM * DD;
  u16* qkv = wt + (size_t)3 * DD * DD;
  u16* vtg = qkv + (size_t)3 * MM * DD;

  convert_x<<<2048, 256, 0, stream>>>(x, xs);
  convert_w<<<dim3(16, 16, 3), 256, 0, stream>>>(wq, wk, wv, wt);
  qkv_gemm<<<dim3(64, 8, 3), 256, 0, stream>>>(xs, wt, qkv);
  vtrans<<<dim3(32, HH, BB), 256, 0, stream>>>(qkv + (size_t)2 * MM * DD, vtg);
  attn_kernel<<<dim3(32, HH, BB), 256, 0, stream>>>(qkv, vtg, out);
}